// Round 1
// baseline (126.303 us; speedup 1.0000x reference)
//
#include <hip/hip_runtime.h>
#include <math.h>

#define NB 32
#define CC 64
#define LL 1024
#define EPS 1e-6f
#define SCALE 14.42695040888963f   // 10*log2(e): exp(10*s) == exp2(SCALE*s)

typedef __attribute__((ext_vector_type(8))) __bf16 bf16x8;
typedef __attribute__((ext_vector_type(4))) float f32x4;

#define GLB(p) ((__attribute__((address_space(1))) void*)(p))
#define LDS(p) ((__attribute__((address_space(3))) void*)(p))

// ws byte layout:
//   At      @ 0         (4 MB)   bf16 [32][1024][64]  rgb, normalized*SCALE, [l][c]
//   Bt      @ 4194304   (4 MB)   bf16 [32][1024][64]  ir, normalized, [l][c]
//   row_sum @ 8388608   (128 KB) f32[32768]   (final, written by merge)
//   col_sum @ 8519680   (128 KB) f32[32768]
//   row_pk  @ 8650752   (128 KB) u32[32768]  (expbits&~1023)|(1023-j)
//   col_pk  @ 8781824   (128 KB) u32[32768]  (expbits&~1023)|(1023-i)
//   partial @ 8912896   (256 B)  f32[64] loss partials
//   rps     @ 9437184   (256 KB) f32[2][32768]  row-sum partials per j-half
//   rpp     @ 9699328   (256 KB) u32[2][32768]  row-pk  partials per j-half
//   cps     @ 9961472   (2 MB)   f32[32][16][1024] col-sum partials per i-tile
//   cpp     @ 12058624  (2 MB)   u32[32][16][1024] col-pk  partials per i-tile
// No zero-init needed: every scratch word is direct-stored exactly once.

__global__ __launch_bounds__(256) void transpose_norm_kernel(
        const float* __restrict__ rgb, const float* __restrict__ ir,
        __bf16* __restrict__ At, __bf16* __restrict__ Bt) {
    __shared__ float tile[64][65];
    __shared__ float red[4][64];
    __shared__ float rn[64];

    const int t   = threadIdx.x;
    const int blk = blockIdx.x;
    const int in  = blk >> 9;
    const int b   = (blk >> 4) & 31;
    const int l0  = (blk & 15) << 6;
    const float* src = in ? ir : rgb;
    __bf16*      dst = in ? Bt : At;
    const float  sc  = in ? 1.0f : SCALE;   // fold exp2 prescale into rgb side

    const int ll = t & 63, cg = t >> 6;
    const float* sp = src + ((size_t)b << 16) + l0 + ll;
#pragma unroll
    for (int u = 0; u < 16; ++u) {
        int c = cg * 16 + u;
        tile[c][ll] = sp[(size_t)c << 10];
    }
    __syncthreads();

    float ssq = 0.f;
#pragma unroll
    for (int u = 0; u < 16; ++u) {
        float v = tile[cg * 16 + u][ll];
        ssq = fmaf(v, v, ssq);
    }
    red[cg][ll] = ssq;
    __syncthreads();
    if (t < 64) {
        float s = red[0][t] + red[1][t] + red[2][t] + red[3][t];
        rn[t] = sc / fmaxf(sqrtf(s), 1e-12f);
    }
    __syncthreads();

    const int lw  = t >> 2;
    const int cg2 = t & 3;
    const float r = rn[lw];
    bf16x8 v0, v1;
#pragma unroll
    for (int u = 0; u < 8; ++u)
        v0[u] = (__bf16)(tile[cg2 * 16 + u][lw] * r);
#pragma unroll
    for (int u = 0; u < 8; ++u)
        v1[u] = (__bf16)(tile[cg2 * 16 + 8 + u][lw] * r);
    size_t base = ((((size_t)b << 10) + l0 + lw) << 6) + cg2 * 16;
    *(bf16x8*)(dst + base)     = v0;
    *(bf16x8*)(dst + base + 8) = v1;
}

// Single-pass GEMM: S computed ONCE (was twice as S and S^T). Grid 1024 =
// batch(32) x itile(16) x jhalf(2): block owns rows [i0,+64) x cols
// [jh*512,+512). Row stats: in-wave butterfly (unchanged), 2-way j-half
// partials to scratch. Col stats: per-lane 4-row fold -> ds_add_f32 /
// ds_max_u32 into per-block LDS column arrays (each col visited once per
// wave; 16-way same-address atomics per u-iter stay far below the LDS pipe
// budget while we're VALU-bound on exp2+pack), 16-way i-tile partials to
// scratch. A tiny merge kernel folds both. Net: MFMA, staging bytes and
// the dominant per-element exp/pack work all halve for ~+30% inner cost.
//
// Staging structure identical to the verified kernel (r6 lesson: async
// global->LDS via global_load_lds, double-buffered; swizzle on the GLOBAL
// side: segment s of row r lands at slot s^(r&7)).
__global__ __launch_bounds__(256, 4) void gemm_stats_kernel(
        const __bf16* __restrict__ At, const __bf16* __restrict__ Bt,
        float* __restrict__ rps, unsigned* __restrict__ rpp,
        float* __restrict__ cps, unsigned* __restrict__ cpp) {
    __shared__ __bf16 Bs[2][8192];   // 2 x 16 KB (128 rows x 64 bf16)
    __shared__ float    csum[512];
    __shared__ unsigned cpk[512];

    const int t   = threadIdx.x;
    const int blk = blockIdx.x;
    const int jh  = blk & 1;
    const int it  = (blk >> 1) & 15;
    const int bb  = blk >> 5;
    const int i0  = it << 6;
    const int w = t >> 6, lane = t & 63;
    const int m = lane & 15, q = lane >> 4;

    const size_t bbase = (size_t)bb << 16;
    const __bf16* Bg = Bt + bbase + ((size_t)jh << 15);   // + jh*512 rows*64

    // A fragments (held all kernel): row = i0+16w+m, k = q*8 (+32).
    const __bf16* Ap = At + bbase + ((size_t)(i0 + 16 * w + m) << 6) + q * 8;
    const bf16x8 a0 = *(const bf16x8*)(Ap);
    const bf16x8 a1 = *(const bf16x8*)(Ap + 32);

    // Swizzled fragment read offsets (elements).
    const int mbase = m * 64;
    const int s0 = (q ^ (m & 7)) << 3;
    const int s1 = ((q ^ 4) ^ (m & 7)) << 3;

    float    rsum[4] = {0.f, 0.f, 0.f, 0.f};
    unsigned rpk4[4] = {0u, 0u, 0u, 0u};

    // iinv for this thread's 4 rows: K1023 - r, r=0..3 (low 10 bits of pack).
    const unsigned K1023 = 1023u - (unsigned)(i0 + 16 * w + 4 * q);

    // Per-thread staging geometry: row r = rho*32 + (t>>3), seg slot t&7,
    // global seg = slot ^ (r&7).
    const int sr  = t >> 3;
    const int ssl = t & 7;

    // zero col-partial LDS (barrier below covers it)
#pragma unroll
    for (int v = 0; v < 2; ++v) {
        csum[(v << 8) + t] = 0.f;
        cpk[(v << 8) + t]  = 0u;
    }

    // stage chunk 0 -> Bs[0]
#pragma unroll
    for (int rho = 0; rho < 4; ++rho) {
        int r  = rho * 32 + sr;
        int sg = ssl ^ (r & 7);
        const __bf16* gp = Bg + ((size_t)r << 6) + sg * 8;
        __builtin_amdgcn_global_load_lds(GLB(gp), LDS(&Bs[0][(rho << 11) + (w << 9)]),
                                         16, 0, 0);
    }
    __syncthreads();   // chunk 0 ready + LDS cols zeroed

    for (int c = 0; c < 4; ++c) {
        const int cur = c & 1;
        if (c < 3) {   // issue async loads for chunk c+1 into the other buffer
#pragma unroll
            for (int rho = 0; rho < 4; ++rho) {
                int r  = rho * 32 + sr;
                int sg = ssl ^ (r & 7);
                const __bf16* gp = Bg + ((size_t)((c + 1) * 128 + r) << 6) + sg * 8;
                __builtin_amdgcn_global_load_lds(GLB(gp),
                        LDS(&Bs[cur ^ 1][(rho << 11) + (w << 9)]), 16, 0, 0);
            }
        }
        const __bf16* pb0 = &Bs[cur][mbase + s0];
        const __bf16* pb1 = &Bs[cur][mbase + s1];
#pragma unroll
        for (int u = 0; u < 8; ++u) {
            bf16x8 b0 = *(const bf16x8*)(pb0 + (u << 10));
            bf16x8 b1 = *(const bf16x8*)(pb1 + (u << 10));
            f32x4 acc = (f32x4){0.f, 0.f, 0.f, 0.f};
            acc = __builtin_amdgcn_mfma_f32_16x16x32_bf16(a0, b0, acc, 0, 0, 0);
            acc = __builtin_amdgcn_mfma_f32_16x16x32_bf16(a1, b1, acc, 0, 0, 0);
            // C/D layout (verified r2-r6): row = i0+16w+4q+r, col = 16ct+m
            // (ct global: jh folded in).
            const int ct = (jh << 5) + (c << 3) + u;
            const unsigned jinv = 1023u - (unsigned)((ct << 4) + m);
            float cs = 0.f;
            unsigned pc = 0u;
#pragma unroll
            for (int r = 0; r < 4; ++r) {
                float e = __builtin_amdgcn_exp2f(acc[r]);   // SCALE folded into At
                unsigned eb = __float_as_uint(e) & 0xFFFFFC00u;
                rsum[r] += e;
                unsigned pr = eb | jinv;
                rpk4[r] = rpk4[r] > pr ? rpk4[r] : pr;     // v_max_u32
                unsigned pcr = eb + (K1023 - (unsigned)r); // == eb | iinv
                if (r == 0) { cs = e; pc = pcr; }
                else        { cs += e; pc = pc > pcr ? pc : pcr; }
            }
            // col partial: each (wave, jl) visited exactly once per kernel;
            // 4 q-lanes x 4 waves contend per address -> ds atomics.
            const int jl = (c << 7) + (u << 4) + m;
            atomicAdd(&csum[jl], cs);
            atomicMax(&cpk[jl], pc);
        }
        // Orders: (a) chunk c+1's loads complete, (b) all waves done reading
        // buf cur before iteration c+1 re-stages into it.
        __syncthreads();
    }
    // trailing __syncthreads drained lgkmcnt: all col atomics are visible.

    // Row stats: one butterfly over the 16 m-lanes (this j-half complete).
#pragma unroll
    for (int s = 1; s < 16; s <<= 1) {
#pragma unroll
        for (int r = 0; r < 4; ++r) {
            rsum[r] += __shfl_xor(rsum[r], s, 64);
            unsigned o = (unsigned)__shfl_xor((int)rpk4[r], s, 64);
            if (o > rpk4[r]) rpk4[r] = o;
        }
    }
    if (m == 0) {
#pragma unroll
        for (int r = 0; r < 4; ++r) {
            int idx = (bb << 10) + i0 + 16 * w + 4 * q + r;
            rps[(jh << 15) + idx] = rsum[r];
            rpp[(jh << 15) + idx] = rpk4[r];
        }
    }

    // Col partials -> scratch [bb][it][ jh*512 + jl ].
#pragma unroll
    for (int v = 0; v < 2; ++v) {
        int jl = (v << 8) + t;
        int gidx = (((bb << 4) + it) << 10) + (jh << 9) + jl;
        cps[gidx] = csum[jl];
        cpp[gidx] = cpk[jl];
    }
}

// Fold row partials (2 j-halves) and col partials (16 i-tiles) into the
// final stats arrays. Tie-break: umax on packed (bits|inv_index) keeps the
// smaller index on equal truncated value = first-occurrence, matching ref.
__global__ __launch_bounds__(256) void merge_kernel(
        const float* __restrict__ rps, const unsigned* __restrict__ rpp,
        const float* __restrict__ cps, const unsigned* __restrict__ cpp,
        float* __restrict__ row_sum, unsigned* __restrict__ row_pk,
        float* __restrict__ col_sum, unsigned* __restrict__ col_pk) {
    int p = blockIdx.x * 256 + threadIdx.x;   // 32768
    // rows: 2 partials
    float rs = rps[p] + rps[32768 + p];
    unsigned ra = rpp[p], rb = rpp[32768 + p];
    row_sum[p] = rs;
    row_pk[p]  = ra > rb ? ra : rb;
    // cols: 16 partials
    int bb = p >> 10, j = p & 1023;
    const float*    cp = cps + (((size_t)bb << 14) + j);
    const unsigned* cq = cpp + (((size_t)bb << 14) + j);
    float s = 0.f;
    unsigned pk = 0u;
#pragma unroll
    for (int itx = 0; itx < 16; ++itx) {
        s += cp[itx << 10];
        unsigned o = cq[itx << 10];
        pk = pk > o ? pk : o;
    }
    col_sum[p] = s;
    col_pk[p]  = pk;
}

// Reference broadcasting: trailing /(sum+EPS) factors are indexed by ELEMENT
// position, not by argmax. Writes per-block partials (no atomics, no init).
__global__ __launch_bounds__(256) void loss_kernel2(
        const float* __restrict__ row_sum, const unsigned* __restrict__ row_pk,
        const float* __restrict__ col_sum, const unsigned* __restrict__ col_pk,
        float* __restrict__ partial) {
    int t = blockIdx.x * 256 + threadIdx.x;
    float acc = 0.f;
#pragma unroll
    for (int it = 0; it < 4; ++it) {
        int p = t + it * 16384;
        if (p < NB * LL) {
            unsigned pk2 = row_pk[p];
            float m2 = __uint_as_float(pk2 & 0xFFFFFC00u);
            int j = 1023 - (int)(pk2 & 1023u);
            float s2 = row_sum[p];
            float s1 = col_sum[p];
            unsigned pk1 = col_pk[(p & ~1023) + j];
            float m1 = __uint_as_float(pk1 & 0xFFFFFC00u);
            acc += logf((m2 / (s2 + EPS)) * (m1 / (s1 + EPS)));
        } else {
            int p2 = p - NB * LL;
            unsigned pk1 = col_pk[p2];
            float m1 = __uint_as_float(pk1 & 0xFFFFFC00u);
            int i = 1023 - (int)(pk1 & 1023u);
            float s1 = col_sum[p2];
            float s2 = row_sum[p2];
            unsigned pk2 = row_pk[(p2 & ~1023) + i];
            float m2 = __uint_as_float(pk2 & 0xFFFFFC00u);
            acc += logf((m1 / (s1 + EPS)) * (m2 / (s2 + EPS)));
        }
    }
#pragma unroll
    for (int off = 32; off > 0; off >>= 1) acc += __shfl_down(acc, off, 64);
    __shared__ float wsum[4];
    int lane = threadIdx.x & 63, w = threadIdx.x >> 6;
    if (lane == 0) wsum[w] = acc;
    __syncthreads();
    if (threadIdx.x == 0)
        partial[blockIdx.x] = wsum[0] + wsum[1] + wsum[2] + wsum[3];
}

__global__ void finalize_kernel(const float* __restrict__ partial,
                                float* __restrict__ out) {
    float v = partial[threadIdx.x];
#pragma unroll
    for (int off = 32; off > 0; off >>= 1) v += __shfl_down(v, off, 64);
    if (threadIdx.x == 0) out[0] = -v / (float)(2 * NB * LL);
}

extern "C" void kernel_launch(void* const* d_in, const int* in_sizes, int n_in,
                              void* d_out, int out_size, void* d_ws, size_t ws_size,
                              hipStream_t stream) {
    const float* rgb = (const float*)d_in[0];
    const float* ir  = (const float*)d_in[1];
    char* wsb = (char*)d_ws;

    __bf16*   At      = (__bf16*)(wsb);
    __bf16*   Bt      = (__bf16*)(wsb + 4194304);
    float*    row_sum = (float*)(wsb + 8388608);
    float*    col_sum = (float*)(wsb + 8519680);
    unsigned* row_pk  = (unsigned*)(wsb + 8650752);
    unsigned* col_pk  = (unsigned*)(wsb + 8781824);
    float*    partial = (float*)(wsb + 8912896);
    float*    rps     = (float*)(wsb + 9437184);
    unsigned* rpp     = (unsigned*)(wsb + 9699328);
    float*    cps     = (float*)(wsb + 9961472);
    unsigned* cpp     = (unsigned*)(wsb + 12058624);

    transpose_norm_kernel<<<1024, 256, 0, stream>>>(rgb, ir, At, Bt);
    gemm_stats_kernel<<<1024, 256, 0, stream>>>(At, Bt, rps, rpp, cps, cpp);
    merge_kernel<<<128, 256, 0, stream>>>(rps, rpp, cps, cpp,
                                          row_sum, row_pk, col_sum, col_pk);
    loss_kernel2<<<64, 256, 0, stream>>>(row_sum, row_pk, col_sum, col_pk, partial);
    finalize_kernel<<<1, 64, 0, stream>>>(partial, (float*)d_out);
}

// Round 2
// 97.310 us; speedup vs baseline: 1.2979x; 1.2979x over previous
//
#include <hip/hip_runtime.h>
#include <math.h>

#define NB 32
#define CC 64
#define LL 1024
#define EPS 1e-6f
#define SCALE 14.42695040888963f   // 10*log2(e): exp(10*s) == exp2(SCALE*s)

typedef __attribute__((ext_vector_type(8))) __bf16 bf16x8;
typedef __attribute__((ext_vector_type(4))) float f32x4;

#define GLB(p) ((__attribute__((address_space(1))) void*)(p))
#define LDS(p) ((__attribute__((address_space(3))) void*)(p))

// ws byte layout:
//   At      @ 0         (4 MB)   bf16 [32][1024][64]  rgb, normalized*SCALE, [l][c]
//   Bt      @ 4194304   (4 MB)   bf16 [32][1024][64]  ir, normalized, [l][c]
//   row_sum @ 8388608   (128 KB) f32[32768]   (final, written by merge)
//   col_sum @ 8519680   (128 KB) f32[32768]
//   row_pk  @ 8650752   (128 KB) u32[32768]  (expbits&~1023)|(1023-j)
//   col_pk  @ 8781824   (128 KB) u32[32768]  (expbits&~1023)|(1023-i)
//   partial @ 8912896   (256 B)  f32[64] loss partials
//   rps     @ 9437184   (256 KB) f32[2][32768]    row-sum partials per j-half
//   rpp     @ 9699328   (256 KB) u32[2][32768]    row-pk  partials per j-half
//   cps     @ 9961472   (8 MB)   f32[32][16][4][1024] col-sum partials (itile,wave)
//   cpp     @ 18350080  (8 MB)   u32[32][16][4][1024] col-pk  partials (itile,wave)
// No zero-init needed: every scratch word is direct-stored exactly once.

__global__ __launch_bounds__(256) void transpose_norm_kernel(
        const float* __restrict__ rgb, const float* __restrict__ ir,
        __bf16* __restrict__ At, __bf16* __restrict__ Bt) {
    __shared__ float tile[64][65];
    __shared__ float red[4][64];
    __shared__ float rn[64];

    const int t   = threadIdx.x;
    const int blk = blockIdx.x;
    const int in  = blk >> 9;
    const int b   = (blk >> 4) & 31;
    const int l0  = (blk & 15) << 6;
    const float* src = in ? ir : rgb;
    __bf16*      dst = in ? Bt : At;
    const float  sc  = in ? 1.0f : SCALE;   // fold exp2 prescale into rgb side

    const int ll = t & 63, cg = t >> 6;
    const float* sp = src + ((size_t)b << 16) + l0 + ll;
#pragma unroll
    for (int u = 0; u < 16; ++u) {
        int c = cg * 16 + u;
        tile[c][ll] = sp[(size_t)c << 10];
    }
    __syncthreads();

    float ssq = 0.f;
#pragma unroll
    for (int u = 0; u < 16; ++u) {
        float v = tile[cg * 16 + u][ll];
        ssq = fmaf(v, v, ssq);
    }
    red[cg][ll] = ssq;
    __syncthreads();
    if (t < 64) {
        float s = red[0][t] + red[1][t] + red[2][t] + red[3][t];
        rn[t] = sc / fmaxf(sqrtf(s), 1e-12f);
    }
    __syncthreads();

    const int lw  = t >> 2;
    const int cg2 = t & 3;
    const float r = rn[lw];
    bf16x8 v0, v1;
#pragma unroll
    for (int u = 0; u < 8; ++u)
        v0[u] = (__bf16)(tile[cg2 * 16 + u][lw] * r);
#pragma unroll
    for (int u = 0; u < 8; ++u)
        v1[u] = (__bf16)(tile[cg2 * 16 + 8 + u][lw] * r);
    size_t base = ((((size_t)b << 10) + l0 + lw) << 6) + cg2 * 16;
    *(bf16x8*)(dst + base)     = v0;
    *(bf16x8*)(dst + base + 8) = v1;
}

// Single-pass GEMM: S computed ONCE. Grid 1024 = batch(32) x itile(16) x
// jhalf(2): block owns rows [i0,+64) x cols [jh*512,+512).
//
// r7 lesson (126 us regression): in-loop DS atomics for col stats collapsed
// VALUBusy to 14% — same-address ds_atomic serializes 16-way AND in-order DS
// completion gates every subsequent fragment ds_read behind the atomic
// backlog. Fix: each (c,u) column group is visited exactly once per wave, so
// the col partial is a pure REGISTER assignment (cs8/cp8, compile-time
// indexed under the unrolled u-loop). Chunk tail: shfl_xor(16,32) butterfly
// over the q lanes (VALU pipe, no conflicts), then q==0 lanes store per-wave
// partials straight to global. Zero atomics anywhere.
//
// Staging structure identical to the verified r6 kernel: async global->LDS
// via global_load_lds, double-buffered; swizzle on the GLOBAL side (segment
// s of row r lands at slot s^(r&7)); one barrier per chunk.
__global__ __launch_bounds__(256, 4) void gemm_stats_kernel(
        const __bf16* __restrict__ At, const __bf16* __restrict__ Bt,
        float* __restrict__ rps, unsigned* __restrict__ rpp,
        float* __restrict__ cps, unsigned* __restrict__ cpp) {
    __shared__ __bf16 Bs[2][8192];   // 2 x 16 KB (128 rows x 64 bf16)

    const int t   = threadIdx.x;
    const int blk = blockIdx.x;
    const int jh  = blk & 1;
    const int it  = (blk >> 1) & 15;
    const int bb  = blk >> 5;
    const int i0  = it << 6;
    const int w = t >> 6, lane = t & 63;
    const int m = lane & 15, q = lane >> 4;

    const size_t bbase = (size_t)bb << 16;
    const __bf16* Bg = Bt + bbase + ((size_t)jh << 15);   // + jh*512 rows*64

    // A fragments (held all kernel): row = i0+16w+m, k = q*8 (+32).
    const __bf16* Ap = At + bbase + ((size_t)(i0 + 16 * w + m) << 6) + q * 8;
    const bf16x8 a0 = *(const bf16x8*)(Ap);
    const bf16x8 a1 = *(const bf16x8*)(Ap + 32);

    // Swizzled fragment read offsets (elements).
    const int mbase = m * 64;
    const int s0 = (q ^ (m & 7)) << 3;
    const int s1 = ((q ^ 4) ^ (m & 7)) << 3;

    float    rsum[4] = {0.f, 0.f, 0.f, 0.f};
    unsigned rpk4[4] = {0u, 0u, 0u, 0u};

    // iinv for this thread's 4 rows: K1023 - r, r=0..3 (low 10 bits of pack).
    const unsigned K1023 = 1023u - (unsigned)(i0 + 16 * w + 4 * q);

    // Per-wave col-partial base: [bb][it][w][1024 cols].
    const int cwbase = ((((bb << 4) + it) << 2) + w) << 10;

    // Per-thread staging geometry: row r = rho*32 + (t>>3), seg slot t&7,
    // global seg = slot ^ (r&7).
    const int sr  = t >> 3;
    const int ssl = t & 7;

    // stage chunk 0 -> Bs[0]
#pragma unroll
    for (int rho = 0; rho < 4; ++rho) {
        int r  = rho * 32 + sr;
        int sg = ssl ^ (r & 7);
        const __bf16* gp = Bg + ((size_t)r << 6) + sg * 8;
        __builtin_amdgcn_global_load_lds(GLB(gp), LDS(&Bs[0][(rho << 11) + (w << 9)]),
                                         16, 0, 0);
    }
    __syncthreads();   // chunk 0 ready

    for (int c = 0; c < 4; ++c) {
        const int cur = c & 1;
        if (c < 3) {   // issue async loads for chunk c+1 into the other buffer
#pragma unroll
            for (int rho = 0; rho < 4; ++rho) {
                int r  = rho * 32 + sr;
                int sg = ssl ^ (r & 7);
                const __bf16* gp = Bg + ((size_t)((c + 1) * 128 + r) << 6) + sg * 8;
                __builtin_amdgcn_global_load_lds(GLB(gp),
                        LDS(&Bs[cur ^ 1][(rho << 11) + (w << 9)]), 16, 0, 0);
            }
        }
        float    cs8[8];
        unsigned cp8[8];
        const __bf16* pb0 = &Bs[cur][mbase + s0];
        const __bf16* pb1 = &Bs[cur][mbase + s1];
#pragma unroll
        for (int u = 0; u < 8; ++u) {
            bf16x8 b0 = *(const bf16x8*)(pb0 + (u << 10));
            bf16x8 b1 = *(const bf16x8*)(pb1 + (u << 10));
            f32x4 acc = (f32x4){0.f, 0.f, 0.f, 0.f};
            acc = __builtin_amdgcn_mfma_f32_16x16x32_bf16(a0, b0, acc, 0, 0, 0);
            acc = __builtin_amdgcn_mfma_f32_16x16x32_bf16(a1, b1, acc, 0, 0, 0);
            // C/D layout (verified r2-r6): row = i0+16w+4q+r, col = 16ct+m
            // (ct global: jh folded in).
            const int ct = (jh << 5) + (c << 3) + u;
            const unsigned jinv = 1023u - (unsigned)((ct << 4) + m);
            float cs = 0.f;
            unsigned pc = 0u;
#pragma unroll
            for (int r = 0; r < 4; ++r) {
                float e = __builtin_amdgcn_exp2f(acc[r]);   // SCALE folded into At
                unsigned eb = __float_as_uint(e) & 0xFFFFFC00u;
                rsum[r] += e;
                unsigned pr = eb | jinv;
                rpk4[r] = rpk4[r] > pr ? rpk4[r] : pr;     // v_max_u32
                unsigned pcr = eb + (K1023 - (unsigned)r); // == eb | iinv
                if (r == 0) { cs = e; pc = pcr; }
                else        { cs += e; pc = pc > pcr ? pc : pcr; }
            }
            cs8[u] = cs;   // compile-time index (u-loop unrolled) — stays in regs
            cp8[u] = pc;
        }
        // Chunk tail: fold the 4 q-lanes (rows 16w..16w+15 complete), store
        // per-wave col partials. Fire-and-forget stores; drained by the
        // barrier's vmcnt(0) alongside the staging loads.
#pragma unroll
        for (int u = 0; u < 8; ++u) {
            float s = cs8[u];
            s += __shfl_xor(s, 16, 64);
            s += __shfl_xor(s, 32, 64);
            unsigned p = cp8[u];
            unsigned o = (unsigned)__shfl_xor((int)p, 16, 64);
            if (o > p) p = o;
            o = (unsigned)__shfl_xor((int)p, 32, 64);
            if (o > p) p = o;
            if (q == 0) {
                int gidx = cwbase + (jh << 9) + (((c << 3) + u) << 4) + m;
                cps[gidx] = s;
                cpp[gidx] = p;
            }
        }
        // Orders: (a) chunk c+1's loads complete, (b) all waves done reading
        // buf cur before iteration c+1 re-stages into it.
        __syncthreads();
    }

    // Row stats: one butterfly over the 16 m-lanes (this j-half complete).
#pragma unroll
    for (int s = 1; s < 16; s <<= 1) {
#pragma unroll
        for (int r = 0; r < 4; ++r) {
            rsum[r] += __shfl_xor(rsum[r], s, 64);
            unsigned o = (unsigned)__shfl_xor((int)rpk4[r], s, 64);
            if (o > rpk4[r]) rpk4[r] = o;
        }
    }
    if (m == 0) {
#pragma unroll
        for (int r = 0; r < 4; ++r) {
            int idx = (bb << 10) + i0 + 16 * w + 4 * q + r;
            rps[(jh << 15) + idx] = rsum[r];
            rpp[(jh << 15) + idx] = rpk4[r];
        }
    }
}

// Fold row partials (2 j-halves) and col partials (64 = 16 itiles x 4 waves)
// into the final stats arrays. Tie-break: umax on packed (bits|inv_index)
// keeps the smaller index on equal truncated value = first-occurrence,
// matching ref.
__global__ __launch_bounds__(256) void merge_kernel(
        const float* __restrict__ rps, const unsigned* __restrict__ rpp,
        const float* __restrict__ cps, const unsigned* __restrict__ cpp,
        float* __restrict__ row_sum, unsigned* __restrict__ row_pk,
        float* __restrict__ col_sum, unsigned* __restrict__ col_pk) {
    int p = blockIdx.x * 256 + threadIdx.x;   // 32768
    // rows: 2 partials
    float rs = rps[p] + rps[32768 + p];
    unsigned ra = rpp[p], rb = rpp[32768 + p];
    row_sum[p] = rs;
    row_pk[p]  = ra > rb ? ra : rb;
    // cols: 64 partials, stride 1024 dwords (j contiguous -> coalesced)
    int bb = p >> 10, j = p & 1023;
    const float*    cp = cps + (((size_t)bb << 16) + j);
    const unsigned* cq = cpp + (((size_t)bb << 16) + j);
    float s = 0.f;
    unsigned pk = 0u;
#pragma unroll
    for (int k = 0; k < 64; ++k) {
        s += cp[(size_t)k << 10];
        unsigned o = cq[(size_t)k << 10];
        pk = pk > o ? pk : o;
    }
    col_sum[p] = s;
    col_pk[p]  = pk;
}

// Reference broadcasting: trailing /(sum+EPS) factors are indexed by ELEMENT
// position, not by argmax. Writes per-block partials (no atomics, no init).
__global__ __launch_bounds__(256) void loss_kernel2(
        const float* __restrict__ row_sum, const unsigned* __restrict__ row_pk,
        const float* __restrict__ col_sum, const unsigned* __restrict__ col_pk,
        float* __restrict__ partial) {
    int t = blockIdx.x * 256 + threadIdx.x;
    float acc = 0.f;
#pragma unroll
    for (int it = 0; it < 4; ++it) {
        int p = t + it * 16384;
        if (p < NB * LL) {
            unsigned pk2 = row_pk[p];
            float m2 = __uint_as_float(pk2 & 0xFFFFFC00u);
            int j = 1023 - (int)(pk2 & 1023u);
            float s2 = row_sum[p];
            float s1 = col_sum[p];
            unsigned pk1 = col_pk[(p & ~1023) + j];
            float m1 = __uint_as_float(pk1 & 0xFFFFFC00u);
            acc += logf((m2 / (s2 + EPS)) * (m1 / (s1 + EPS)));
        } else {
            int p2 = p - NB * LL;
            unsigned pk1 = col_pk[p2];
            float m1 = __uint_as_float(pk1 & 0xFFFFFC00u);
            int i = 1023 - (int)(pk1 & 1023u);
            float s1 = col_sum[p2];
            float s2 = row_sum[p2];
            unsigned pk2 = row_pk[(p2 & ~1023) + i];
            float m2 = __uint_as_float(pk2 & 0xFFFFFC00u);
            acc += logf((m1 / (s1 + EPS)) * (m2 / (s2 + EPS)));
        }
    }
#pragma unroll
    for (int off = 32; off > 0; off >>= 1) acc += __shfl_down(acc, off, 64);
    __shared__ float wsum[4];
    int lane = threadIdx.x & 63, w = threadIdx.x >> 6;
    if (lane == 0) wsum[w] = acc;
    __syncthreads();
    if (threadIdx.x == 0)
        partial[blockIdx.x] = wsum[0] + wsum[1] + wsum[2] + wsum[3];
}

__global__ void finalize_kernel(const float* __restrict__ partial,
                                float* __restrict__ out) {
    float v = partial[threadIdx.x];
#pragma unroll
    for (int off = 32; off > 0; off >>= 1) v += __shfl_down(v, off, 64);
    if (threadIdx.x == 0) out[0] = -v / (float)(2 * NB * LL);
}

extern "C" void kernel_launch(void* const* d_in, const int* in_sizes, int n_in,
                              void* d_out, int out_size, void* d_ws, size_t ws_size,
                              hipStream_t stream) {
    const float* rgb = (const float*)d_in[0];
    const float* ir  = (const float*)d_in[1];
    char* wsb = (char*)d_ws;

    __bf16*   At      = (__bf16*)(wsb);
    __bf16*   Bt      = (__bf16*)(wsb + 4194304);
    float*    row_sum = (float*)(wsb + 8388608);
    float*    col_sum = (float*)(wsb + 8519680);
    unsigned* row_pk  = (unsigned*)(wsb + 8650752);
    unsigned* col_pk  = (unsigned*)(wsb + 8781824);
    float*    partial = (float*)(wsb + 8912896);
    float*    rps     = (float*)(wsb + 9437184);
    unsigned* rpp     = (unsigned*)(wsb + 9699328);
    float*    cps     = (float*)(wsb + 9961472);
    unsigned* cpp     = (unsigned*)(wsb + 18350080);

    transpose_norm_kernel<<<1024, 256, 0, stream>>>(rgb, ir, At, Bt);
    gemm_stats_kernel<<<1024, 256, 0, stream>>>(At, Bt, rps, rpp, cps, cpp);
    merge_kernel<<<128, 256, 0, stream>>>(rps, rpp, cps, cpp,
                                          row_sum, row_pk, col_sum, col_pk);
    loss_kernel2<<<64, 256, 0, stream>>>(row_sum, row_pk, col_sum, col_pk, partial);
    finalize_kernel<<<1, 64, 0, stream>>>(partial, (float*)d_out);
}